// Round 1
// baseline (170.216 us; speedup 1.0000x reference)
//
#include <hip/hip_runtime.h>
#include <hip/hip_bf16.h>

#define BSZ   4096
#define DIM   512
#define NROW  8192
#define INV_T 14.285714285714285f

typedef __bf16 bf16x8 __attribute__((ext_vector_type(8)));
typedef float  f32x4  __attribute__((ext_vector_type(4)));

#define GLOAD_LDS16(gp, lp) __builtin_amdgcn_global_load_lds( \
    (const __attribute__((address_space(1))) unsigned int*)(const void*)(gp), \
    (__attribute__((address_space(3))) unsigned int*)(void*)(lp), 16, 0, 0)

// ---------------------------------------------------------------------------
// Kernel 1: row-normalize z1,z2 -> bf16 F[8192][512]; accumulate sum of
// positive-pair cosine sims (fp32, un-divided by tau) into *possum.
// One wave per row pair.
// ---------------------------------------------------------------------------
__device__ inline void store_bf4(__hip_bfloat16* p, float4 v, float s) {
    union { __hip_bfloat16 h[4]; uint2 u; } t;
    t.h[0] = __float2bfloat16(v.x * s);
    t.h[1] = __float2bfloat16(v.y * s);
    t.h[2] = __float2bfloat16(v.z * s);
    t.h[3] = __float2bfloat16(v.w * s);
    *(uint2*)p = t.u;
}

__global__ __launch_bounds__(256) void nt_norm(const float* __restrict__ z1,
                                               const float* __restrict__ z2,
                                               __hip_bfloat16* __restrict__ F,
                                               float* __restrict__ possum) {
    const int wid  = threadIdx.x >> 6;
    const int lane = threadIdx.x & 63;
    const int row  = blockIdx.x * 4 + wid;          // 0..4095

    const float4* a4 = (const float4*)(z1 + (size_t)row * DIM);
    const float4* b4 = (const float4*)(z2 + (size_t)row * DIM);
    float4 a0 = a4[lane], a1 = a4[64 + lane];
    float4 b0 = b4[lane], b1 = b4[64 + lane];

    float s1 = a0.x*a0.x + a0.y*a0.y + a0.z*a0.z + a0.w*a0.w
             + a1.x*a1.x + a1.y*a1.y + a1.z*a1.z + a1.w*a1.w;
    float s2 = b0.x*b0.x + b0.y*b0.y + b0.z*b0.z + b0.w*b0.w
             + b1.x*b1.x + b1.y*b1.y + b1.z*b1.z + b1.w*b1.w;
    float d  = a0.x*b0.x + a0.y*b0.y + a0.z*b0.z + a0.w*b0.w
             + a1.x*b1.x + a1.y*b1.y + a1.z*b1.z + a1.w*b1.w;

    #pragma unroll
    for (int off = 32; off; off >>= 1) {
        s1 += __shfl_xor(s1, off);
        s2 += __shfl_xor(s2, off);
        d  += __shfl_xor(d,  off);
    }

    const float inv1 = 1.0f / fmaxf(sqrtf(s1), 1e-12f);
    const float inv2 = 1.0f / fmaxf(sqrtf(s2), 1e-12f);

    __hip_bfloat16* F1 = F + (size_t)row * DIM;
    __hip_bfloat16* F2 = F + (size_t)(BSZ + row) * DIM;
    store_bf4(F1 + lane * 4,       a0, inv1);
    store_bf4(F1 + 256 + lane * 4, a1, inv1);
    store_bf4(F2 + lane * 4,       b0, inv2);
    store_bf4(F2 + 256 + lane * 4, b1, inv2);

    if (lane == 0) atomicAdd(possum, d * inv1 * inv2);
}

// ---------------------------------------------------------------------------
// Kernel 2: for upper-triangular 128x128 tile pairs (r<=c) of S = F F^T,
// compute exp((dot-1)/tau) and accumulate row sums (and col sums for r!=c)
// into rowsum[8192] via atomicAdd.
// 256 threads = 4 waves in 2x2; mfma_f32_16x16x32_bf16; BK=64 LDS staging
// via global_load_lds width 16 (m97 structure).
// ---------------------------------------------------------------------------
__global__ __launch_bounds__(256) void simexp(const __hip_bfloat16* __restrict__ F,
                                              float* __restrict__ rowsum) {
    __shared__ __align__(16) short As[128 * 64];
    __shared__ __align__(16) short Bs[128 * 64];

    // map linear block id -> (r, c) with r <= c over 64 row/col tiles
    int t = blockIdx.x;
    int r = 0, base = 0;
    while (t >= base + (64 - r)) { base += 64 - r; ++r; }
    const int c = r + (t - base);

    const int wid  = threadIdx.x >> 6;
    const int lane = threadIdx.x & 63;
    const int wr   = wid >> 1;            // wave row (0..1) -> 64 rows
    const int wc   = wid & 1;             // wave col (0..1) -> 64 cols
    const size_t row0 = (size_t)r * 128;
    const size_t col0 = (size_t)c * 128;

    f32x4 acc[4][4] = {};

    for (int kt = 0; kt < 8; ++kt) {
        const __hip_bfloat16* Ag = F + row0 * DIM + kt * 64;
        const __hip_bfloat16* Bg = F + col0 * DIM + kt * 64;
        #pragma unroll
        for (int ch = 0; ch < 4; ++ch) {
            const int i  = ch * 256 + threadIdx.x;  // 16B chunk id, 0..1023
            const int rr = i >> 3;                  // tile row
            const int ec = (i & 7) * 8;             // element col within BK
            const int seg = ch * 256 + wid * 64;    // wave-uniform chunk base
            GLOAD_LDS16(Ag + (size_t)rr * DIM + ec, As + seg * 8);
            GLOAD_LDS16(Bg + (size_t)rr * DIM + ec, Bs + seg * 8);
        }
        __syncthreads();

        #pragma unroll
        for (int ks = 0; ks < 2; ++ks) {
            bf16x8 a[4], b[4];
            #pragma unroll
            for (int m = 0; m < 4; ++m) {
                const int rr = wr * 64 + m * 16 + (lane & 15);
                const int kb = ks * 64 + ((lane >> 4) << 4);
                a[m] = *(const bf16x8*)((const char*)As + rr * 128 + kb);
            }
            #pragma unroll
            for (int n = 0; n < 4; ++n) {
                const int rr = wc * 64 + n * 16 + (lane & 15);
                const int kb = ks * 64 + ((lane >> 4) << 4);
                b[n] = *(const bf16x8*)((const char*)Bs + rr * 128 + kb);
            }
            #pragma unroll
            for (int m = 0; m < 4; ++m)
                #pragma unroll
                for (int n = 0; n < 4; ++n)
                    acc[m][n] = __builtin_amdgcn_mfma_f32_16x16x32_bf16(
                        a[m], b[n], acc[m][n], 0, 0, 0);
        }
        __syncthreads();
    }

    // epilogue: p = exp((dot - 1)/tau); C/D map: col = lane&15,
    // row = (lane>>4)*4 + j  (guide-verified m89/m91)
    float p[4][4][4];
    #pragma unroll
    for (int m = 0; m < 4; ++m)
        #pragma unroll
        for (int n = 0; n < 4; ++n)
            #pragma unroll
            for (int j = 0; j < 4; ++j)
                p[m][n][j] = __expf((acc[m][n][j] - 1.0f) * INV_T);

    // row sums: sum over this wave's 64 cols, per row
    #pragma unroll
    for (int m = 0; m < 4; ++m)
        #pragma unroll
        for (int j = 0; j < 4; ++j) {
            float rs = p[m][0][j] + p[m][1][j] + p[m][2][j] + p[m][3][j];
            rs += __shfl_xor(rs, 1);
            rs += __shfl_xor(rs, 2);
            rs += __shfl_xor(rs, 4);
            rs += __shfl_xor(rs, 8);
            if ((lane & 15) == 0) {
                const int grow = (int)row0 + wr * 64 + m * 16 + ((lane >> 4) << 2) + j;
                atomicAdd(&rowsum[grow], rs);
            }
        }

    // col sums (transpose contribution) for off-diagonal tile pairs
    if (r != c) {
        #pragma unroll
        for (int n = 0; n < 4; ++n) {
            float cs = 0.f;
            #pragma unroll
            for (int m = 0; m < 4; ++m)
                #pragma unroll
                for (int j = 0; j < 4; ++j)
                    cs += p[m][n][j];
            cs += __shfl_xor(cs, 16);
            cs += __shfl_xor(cs, 32);
            if (lane < 16) {
                const int gcol = (int)col0 + wc * 64 + n * 16 + lane;
                atomicAdd(&rowsum[gcol], cs);
            }
        }
    }
}

// ---------------------------------------------------------------------------
// Kernel 3: loss = 1/tau + mean(log E_i) - possum/tau/4096
// ---------------------------------------------------------------------------
__global__ __launch_bounds__(256) void nt_final(const float* __restrict__ rowsum,
                                                const float* __restrict__ possum,
                                                float* __restrict__ out) {
    __shared__ float red[256];
    float s = 0.f;
    for (int i = threadIdx.x; i < NROW; i += 256) s += logf(rowsum[i]);
    red[threadIdx.x] = s;
    __syncthreads();
    for (int off = 128; off; off >>= 1) {
        if (threadIdx.x < off) red[threadIdx.x] += red[threadIdx.x + off];
        __syncthreads();
    }
    if (threadIdx.x == 0) {
        out[0] = INV_T + red[0] / (float)NROW - possum[0] * INV_T / (float)BSZ;
    }
}

extern "C" void kernel_launch(void* const* d_in, const int* in_sizes, int n_in,
                              void* d_out, int out_size, void* d_ws, size_t ws_size,
                              hipStream_t stream) {
    const float* z1 = (const float*)d_in[0];
    const float* z2 = (const float*)d_in[1];
    // d_in[2] (labels) unused by the reference computation

    __hip_bfloat16* F = (__hip_bfloat16*)d_ws;
    const size_t FBYTES = (size_t)NROW * DIM * sizeof(__hip_bfloat16);  // 8 MiB
    float* rowsum = (float*)((char*)d_ws + FBYTES);
    float* possum = rowsum + NROW;

    hipMemsetAsync(rowsum, 0, (NROW + 1) * sizeof(float), stream);
    nt_norm<<<dim3(BSZ / 4), dim3(256), 0, stream>>>(z1, z2, F, possum);
    simexp<<<dim3(2080), dim3(256), 0, stream>>>(F, rowsum);
    nt_final<<<dim3(1), dim3(256), 0, stream>>>(rowsum, possum, (float*)d_out);
}

// Round 2
// 122.289 us; speedup vs baseline: 1.3919x; 1.3919x over previous
//
#include <hip/hip_runtime.h>
#include <hip/hip_bf16.h>

#define BSZ   4096
#define DIM   512
#define NROW  8192
#define NBLK_NORM (BSZ / 4)
#define INV_T 14.285714285714285f

typedef __bf16 bf16x8 __attribute__((ext_vector_type(8)));
typedef float  f32x4  __attribute__((ext_vector_type(4)));

#define GLOAD_LDS16(gp, lp) __builtin_amdgcn_global_load_lds( \
    (const __attribute__((address_space(1))) unsigned int*)(const void*)(gp), \
    (__attribute__((address_space(3))) unsigned int*)(void*)(lp), 16, 0, 0)

// ---------------------------------------------------------------------------
// Kernel 1: row-normalize z1,z2 -> bf16 F[8192][512]; per-block positive-pair
// dot partials -> posbuf[block] (no atomics).
// ---------------------------------------------------------------------------
__device__ inline void store_bf4(__hip_bfloat16* p, float4 v, float s) {
    union { __hip_bfloat16 h[4]; uint2 u; } t;
    t.h[0] = __float2bfloat16(v.x * s);
    t.h[1] = __float2bfloat16(v.y * s);
    t.h[2] = __float2bfloat16(v.z * s);
    t.h[3] = __float2bfloat16(v.w * s);
    *(uint2*)p = t.u;
}

__global__ __launch_bounds__(256) void nt_norm(const float* __restrict__ z1,
                                               const float* __restrict__ z2,
                                               __hip_bfloat16* __restrict__ F,
                                               float* __restrict__ posbuf) {
    __shared__ float pd[4];
    const int wid  = threadIdx.x >> 6;
    const int lane = threadIdx.x & 63;
    const int row  = blockIdx.x * 4 + wid;          // 0..4095

    const float4* a4 = (const float4*)(z1 + (size_t)row * DIM);
    const float4* b4 = (const float4*)(z2 + (size_t)row * DIM);
    float4 a0 = a4[lane], a1 = a4[64 + lane];
    float4 b0 = b4[lane], b1 = b4[64 + lane];

    float s1 = a0.x*a0.x + a0.y*a0.y + a0.z*a0.z + a0.w*a0.w
             + a1.x*a1.x + a1.y*a1.y + a1.z*a1.z + a1.w*a1.w;
    float s2 = b0.x*b0.x + b0.y*b0.y + b0.z*b0.z + b0.w*b0.w
             + b1.x*b1.x + b1.y*b1.y + b1.z*b1.z + b1.w*b1.w;
    float d  = a0.x*b0.x + a0.y*b0.y + a0.z*b0.z + a0.w*b0.w
             + a1.x*b1.x + a1.y*b1.y + a1.z*b1.z + a1.w*b1.w;

    #pragma unroll
    for (int off = 32; off; off >>= 1) {
        s1 += __shfl_xor(s1, off);
        s2 += __shfl_xor(s2, off);
        d  += __shfl_xor(d,  off);
    }

    const float inv1 = 1.0f / fmaxf(sqrtf(s1), 1e-12f);
    const float inv2 = 1.0f / fmaxf(sqrtf(s2), 1e-12f);

    __hip_bfloat16* F1 = F + (size_t)row * DIM;
    __hip_bfloat16* F2 = F + (size_t)(BSZ + row) * DIM;
    store_bf4(F1 + lane * 4,       a0, inv1);
    store_bf4(F1 + 256 + lane * 4, a1, inv1);
    store_bf4(F2 + lane * 4,       b0, inv2);
    store_bf4(F2 + 256 + lane * 4, b1, inv2);

    if (lane == 0) pd[wid] = d * inv1 * inv2;
    __syncthreads();
    if (threadIdx.x == 0)
        posbuf[blockIdx.x] = pd[0] + pd[1] + pd[2] + pd[3];
}

// ---------------------------------------------------------------------------
// Kernel 2: upper-triangular 128x128 tile pairs (r<=c) of S = F F^T;
// p = exp((dot-1)/tau); row sums (and col sums for r!=c) -> rowsum[] atomics.
// 4 waves 2x2, mfma_f32_16x16x32_bf16, BK=64, DOUBLE-BUFFERED 2-phase
// prefetch: STAGE(next) issued before compute(cur), one sync per K-step.
// ---------------------------------------------------------------------------
__device__ __forceinline__ void stage_tiles(const __hip_bfloat16* __restrict__ Ag,
                                            const __hip_bfloat16* __restrict__ Bg,
                                            short* Asb, short* Bsb,
                                            int tid, int wid) {
    #pragma unroll
    for (int ch = 0; ch < 4; ++ch) {
        const int i   = ch * 256 + tid;   // 16B chunk id, 0..1023
        const int rr  = i >> 3;           // tile row
        const int ec  = (i & 7) * 8;      // element col within BK
        const int seg = ch * 256 + wid * 64;  // wave-uniform chunk base
        GLOAD_LDS16(Ag + (size_t)rr * DIM + ec, Asb + seg * 8);
        GLOAD_LDS16(Bg + (size_t)rr * DIM + ec, Bsb + seg * 8);
    }
}

__global__ __launch_bounds__(256) void simexp(const __hip_bfloat16* __restrict__ F,
                                              float* __restrict__ rowsum) {
    __shared__ __align__(16) short As[2][128 * 64];   // 32 KB
    __shared__ __align__(16) short Bs[2][128 * 64];   // 32 KB

    // map linear block id -> (r, c) with r <= c over 64 row/col tiles
    int t = blockIdx.x;
    int r = 0, base = 0;
    while (t >= base + (64 - r)) { base += 64 - r; ++r; }
    const int c = r + (t - base);

    const int tid  = threadIdx.x;
    const int wid  = tid >> 6;
    const int lane = tid & 63;
    const int wr   = wid >> 1;            // wave row (0..1) -> 64 rows
    const int wc   = wid & 1;             // wave col (0..1) -> 64 cols
    const size_t row0 = (size_t)r * 128;
    const size_t col0 = (size_t)c * 128;
    const __hip_bfloat16* Abase = F + row0 * DIM;
    const __hip_bfloat16* Bbase = F + col0 * DIM;

    f32x4 acc[4][4] = {};

    // prologue: stage K-step 0 into buffer 0
    stage_tiles(Abase, Bbase, As[0], Bs[0], tid, wid);
    __syncthreads();

    for (int kt = 0; kt < 8; ++kt) {
        const int cur = kt & 1;
        if (kt < 7)   // prefetch next K-step into the other buffer
            stage_tiles(Abase + (kt + 1) * 64, Bbase + (kt + 1) * 64,
                        As[cur ^ 1], Bs[cur ^ 1], tid, wid);

        const short* Ac = As[cur];
        const short* Bc = Bs[cur];
        #pragma unroll
        for (int ks = 0; ks < 2; ++ks) {
            bf16x8 a[4], b[4];
            #pragma unroll
            for (int m = 0; m < 4; ++m) {
                const int rr = wr * 64 + m * 16 + (lane & 15);
                const int kb = ks * 64 + ((lane >> 4) << 4);
                a[m] = *(const bf16x8*)((const char*)Ac + rr * 128 + kb);
            }
            #pragma unroll
            for (int n = 0; n < 4; ++n) {
                const int rr = wc * 64 + n * 16 + (lane & 15);
                const int kb = ks * 64 + ((lane >> 4) << 4);
                b[n] = *(const bf16x8*)((const char*)Bc + rr * 128 + kb);
            }
            #pragma unroll
            for (int m = 0; m < 4; ++m)
                #pragma unroll
                for (int n = 0; n < 4; ++n)
                    acc[m][n] = __builtin_amdgcn_mfma_f32_16x16x32_bf16(
                        a[m], b[n], acc[m][n], 0, 0, 0);
        }
        __syncthreads();   // drains vmcnt (prefetch flew under the MFMAs)
    }

    // epilogue: p = exp((dot - 1)/tau); C/D map: col = lane&15,
    // row = (lane>>4)*4 + j  (guide-verified m89/m91)
    float p[4][4][4];
    #pragma unroll
    for (int m = 0; m < 4; ++m)
        #pragma unroll
        for (int n = 0; n < 4; ++n)
            #pragma unroll
            for (int j = 0; j < 4; ++j)
                p[m][n][j] = __expf((acc[m][n][j] - 1.0f) * INV_T);

    // row sums: sum over this wave's 64 cols, per row
    #pragma unroll
    for (int m = 0; m < 4; ++m)
        #pragma unroll
        for (int j = 0; j < 4; ++j) {
            float rs = p[m][0][j] + p[m][1][j] + p[m][2][j] + p[m][3][j];
            rs += __shfl_xor(rs, 1);
            rs += __shfl_xor(rs, 2);
            rs += __shfl_xor(rs, 4);
            rs += __shfl_xor(rs, 8);
            if ((lane & 15) == 0) {
                const int grow = (int)row0 + wr * 64 + m * 16 + ((lane >> 4) << 2) + j;
                atomicAdd(&rowsum[grow], rs);
            }
        }

    // col sums (transpose contribution) for off-diagonal tile pairs
    if (r != c) {
        #pragma unroll
        for (int n = 0; n < 4; ++n) {
            float cs = 0.f;
            #pragma unroll
            for (int m = 0; m < 4; ++m)
                #pragma unroll
                for (int j = 0; j < 4; ++j)
                    cs += p[m][n][j];
            cs += __shfl_xor(cs, 16);
            cs += __shfl_xor(cs, 32);
            if (lane < 16) {
                const int gcol = (int)col0 + wc * 64 + n * 16 + lane;
                atomicAdd(&rowsum[gcol], cs);
            }
        }
    }
}

// ---------------------------------------------------------------------------
// Kernel 3: loss = 1/tau + mean(log E_i) - (sum posbuf)/tau/4096
// ---------------------------------------------------------------------------
__global__ __launch_bounds__(256) void nt_final(const float* __restrict__ rowsum,
                                                const float* __restrict__ posbuf,
                                                float* __restrict__ out) {
    __shared__ float redl[256];
    __shared__ float redp[256];
    float s = 0.f, ps = 0.f;
    for (int i = threadIdx.x; i < NROW; i += 256) s += logf(rowsum[i]);
    for (int i = threadIdx.x; i < NBLK_NORM; i += 256) ps += posbuf[i];
    redl[threadIdx.x] = s;
    redp[threadIdx.x] = ps;
    __syncthreads();
    for (int off = 128; off; off >>= 1) {
        if (threadIdx.x < off) {
            redl[threadIdx.x] += redl[threadIdx.x + off];
            redp[threadIdx.x] += redp[threadIdx.x + off];
        }
        __syncthreads();
    }
    if (threadIdx.x == 0) {
        out[0] = INV_T + redl[0] / (float)NROW - redp[0] * INV_T / (float)BSZ;
    }
}

extern "C" void kernel_launch(void* const* d_in, const int* in_sizes, int n_in,
                              void* d_out, int out_size, void* d_ws, size_t ws_size,
                              hipStream_t stream) {
    const float* z1 = (const float*)d_in[0];
    const float* z2 = (const float*)d_in[1];
    // d_in[2] (labels) unused by the reference computation

    __hip_bfloat16* F = (__hip_bfloat16*)d_ws;
    const size_t FBYTES = (size_t)NROW * DIM * sizeof(__hip_bfloat16);  // 8 MiB
    float* rowsum = (float*)((char*)d_ws + FBYTES);
    float* posbuf = rowsum + NROW;

    hipMemsetAsync(rowsum, 0, NROW * sizeof(float), stream);
    nt_norm<<<dim3(NBLK_NORM), dim3(256), 0, stream>>>(z1, z2, F, posbuf);
    simexp<<<dim3(2080), dim3(256), 0, stream>>>(F, rowsum);
    nt_final<<<dim3(1), dim3(256), 0, stream>>>(rowsum, posbuf, (float*)d_out);
}

// Round 4
// 82.496 us; speedup vs baseline: 2.0633x; 1.4824x over previous
//
#include <hip/hip_runtime.h>
#include <hip/hip_bf16.h>

#define BSZ   4096
#define DIM   512
#define NROW  8192
#define NBLK_NORM (BSZ / 4)
#define INV_T 14.285714285714285f

typedef __bf16 bf16x8 __attribute__((ext_vector_type(8)));
typedef float  f32x4  __attribute__((ext_vector_type(4)));

#define GLOAD_LDS16(gp, lp) __builtin_amdgcn_global_load_lds( \
    (const __attribute__((address_space(1))) unsigned int*)(const void*)(gp), \
    (__attribute__((address_space(3))) unsigned int*)(void*)(lp), 16, 0, 0)

// ---------------------------------------------------------------------------
// Kernel 1: row-normalize z1,z2 -> bf16 F[8192][512]; per-block positive-pair
// dot partials -> posbuf[block]; also zeroes rowsum (8 entries/block -> all
// 8192 entries across the 1024 blocks — MUST cover all of rowsum every call).
// ---------------------------------------------------------------------------
__device__ inline void store_bf4(__hip_bfloat16* p, float4 v, float s) {
    union { __hip_bfloat16 h[4]; uint2 u; } t;
    t.h[0] = __float2bfloat16(v.x * s);
    t.h[1] = __float2bfloat16(v.y * s);
    t.h[2] = __float2bfloat16(v.z * s);
    t.h[3] = __float2bfloat16(v.w * s);
    *(uint2*)p = t.u;
}

__global__ __launch_bounds__(256) void nt_norm(const float* __restrict__ z1,
                                               const float* __restrict__ z2,
                                               __hip_bfloat16* __restrict__ F,
                                               float* __restrict__ posbuf,
                                               float* __restrict__ rowsum) {
    __shared__ float pd[4];
    const int wid  = threadIdx.x >> 6;
    const int lane = threadIdx.x & 63;
    const int row  = blockIdx.x * 4 + wid;          // 0..4095

    if (threadIdx.x < 8) rowsum[blockIdx.x * 8 + threadIdx.x] = 0.0f;

    const float4* a4 = (const float4*)(z1 + (size_t)row * DIM);
    const float4* b4 = (const float4*)(z2 + (size_t)row * DIM);
    float4 a0 = a4[lane], a1 = a4[64 + lane];
    float4 b0 = b4[lane], b1 = b4[64 + lane];

    float s1 = a0.x*a0.x + a0.y*a0.y + a0.z*a0.z + a0.w*a0.w
             + a1.x*a1.x + a1.y*a1.y + a1.z*a1.z + a1.w*a1.w;
    float s2 = b0.x*b0.x + b0.y*b0.y + b0.z*b0.z + b0.w*b0.w
             + b1.x*b1.x + b1.y*b1.y + b1.z*b1.z + b1.w*b1.w;
    float d  = a0.x*b0.x + a0.y*b0.y + a0.z*b0.z + a0.w*b0.w
             + a1.x*b1.x + a1.y*b1.y + a1.z*b1.z + a1.w*b1.w;

    #pragma unroll
    for (int off = 32; off; off >>= 1) {
        s1 += __shfl_xor(s1, off);
        s2 += __shfl_xor(s2, off);
        d  += __shfl_xor(d,  off);
    }

    const float inv1 = 1.0f / fmaxf(sqrtf(s1), 1e-12f);
    const float inv2 = 1.0f / fmaxf(sqrtf(s2), 1e-12f);

    __hip_bfloat16* F1 = F + (size_t)row * DIM;
    __hip_bfloat16* F2 = F + (size_t)(BSZ + row) * DIM;
    store_bf4(F1 + lane * 4,       a0, inv1);
    store_bf4(F1 + 256 + lane * 4, a1, inv1);
    store_bf4(F2 + lane * 4,       b0, inv2);
    store_bf4(F2 + 256 + lane * 4, b1, inv2);

    if (lane == 0) pd[wid] = d * inv1 * inv2;
    __syncthreads();
    if (threadIdx.x == 0)
        posbuf[blockIdx.x] = pd[0] + pd[1] + pd[2] + pd[3];
}

// ---------------------------------------------------------------------------
// Kernel 2: upper-tri 128x128 tile pairs of S = F F^T; p = exp((dot-1)/tau);
// row sums (+ col sums for r!=c) -> rowsum[] atomics.
// 4 waves 2x2, mfma 16x16x32 bf16, BK=64, double-buffered 2-phase prefetch.
// (a) XOR-swizzled LDS (byte ^= (row&7)<<4) via pre-swizzled global source +
//     swizzled ds_read (rule #21 involution pair);
// (b) super-tile (8x8 tiles) block order + bijective XCD swizzle so each XCD
//     works a 2 MB L2-resident panel set.
// ---------------------------------------------------------------------------
__device__ __forceinline__ void stage_tiles(const __hip_bfloat16* __restrict__ Ag,
                                            const __hip_bfloat16* __restrict__ Bg,
                                            short* Asb, short* Bsb,
                                            int tid, int wid) {
    #pragma unroll
    for (int ch = 0; ch < 4; ++ch) {
        const int i   = ch * 256 + tid;   // 16B chunk id, 0..1023
        const int rr  = i >> 3;           // tile row
        const int cb  = (i & 7) * 16;     // linear byte col within 128B row
        // inverse-swizzle the SOURCE column so linear LDS dest holds swizzled data
        const int ecs = (cb ^ ((rr & 7) << 4)) >> 1;   // source element col
        const int seg = ch * 256 + wid * 64;           // wave-uniform chunk base
        GLOAD_LDS16(Ag + (size_t)rr * DIM + ecs, Asb + seg * 8);
        GLOAD_LDS16(Bg + (size_t)rr * DIM + ecs, Bsb + seg * 8);
    }
}

__global__ __launch_bounds__(256) void simexp(const __hip_bfloat16* __restrict__ F,
                                              float* __restrict__ rowsum) {
    __shared__ __align__(16) short As[2][128 * 64];   // 32 KB
    __shared__ __align__(16) short Bs[2][128 * 64];   // 32 KB

    // ---- block id -> (r,c), super-tile order + bijective XCD swizzle ----
    int L = (blockIdx.x & 7) * 260 + (blockIdx.x >> 3);
    int rem = L, s_r = 0;
    for (; s_r < 8; ++s_r) {
        const int rowsz = 36 + 64 * (7 - s_r);
        if (rem < rowsz) break;
        rem -= rowsz;
    }
    int s_c, lr, lc;
    if (rem < 36) {              // diagonal super-tile, triangular 8x8
        s_c = s_r;
        lr = 0;
        while (rem >= 8 - lr) { rem -= 8 - lr; ++lr; }
        lc = lr + rem;
    } else {                     // off-diagonal super-tiles
        rem -= 36;
        s_c = s_r + 1 + (rem >> 6);
        const int j = rem & 63;
        lr = j >> 3; lc = j & 7;
    }
    const int r = s_r * 8 + lr;
    const int c = s_c * 8 + lc;

    const int tid  = threadIdx.x;
    const int wid  = tid >> 6;
    const int lane = tid & 63;
    const int wr   = wid >> 1;            // wave row (0..1) -> 64 rows
    const int wc   = wid & 1;             // wave col (0..1) -> 64 cols
    const size_t row0 = (size_t)r * 128;
    const size_t col0 = (size_t)c * 128;
    const __hip_bfloat16* Abase = F + row0 * DIM;
    const __hip_bfloat16* Bbase = F + col0 * DIM;

    f32x4 acc[4][4] = {};

    stage_tiles(Abase, Bbase, As[0], Bs[0], tid, wid);
    __syncthreads();

    for (int kt = 0; kt < 8; ++kt) {
        const int cur = kt & 1;
        if (kt < 7)
            stage_tiles(Abase + (kt + 1) * 64, Bbase + (kt + 1) * 64,
                        As[cur ^ 1], Bs[cur ^ 1], tid, wid);

        const short* Ac = As[cur];
        const short* Bc = Bs[cur];
        #pragma unroll
        for (int ks = 0; ks < 2; ++ks) {
            bf16x8 a[4], b[4];
            const int kb = ks * 64 + ((lane >> 4) << 4);
            const int sw = ((lane & 7) << 4);      // (row&7)<<4, row%8 == lane%8
            #pragma unroll
            for (int m = 0; m < 4; ++m) {
                const int rr = wr * 64 + m * 16 + (lane & 15);
                a[m] = *(const bf16x8*)((const char*)Ac + rr * 128 + (kb ^ sw));
            }
            #pragma unroll
            for (int n = 0; n < 4; ++n) {
                const int rr = wc * 64 + n * 16 + (lane & 15);
                b[n] = *(const bf16x8*)((const char*)Bc + rr * 128 + (kb ^ sw));
            }
            #pragma unroll
            for (int m = 0; m < 4; ++m)
                #pragma unroll
                for (int n = 0; n < 4; ++n)
                    acc[m][n] = __builtin_amdgcn_mfma_f32_16x16x32_bf16(
                        a[m], b[n], acc[m][n], 0, 0, 0);
        }
        __syncthreads();
    }

    // epilogue: p = exp((dot-1)/tau); C/D map col=lane&15, row=(lane>>4)*4+j
    float p[4][4][4];
    #pragma unroll
    for (int m = 0; m < 4; ++m)
        #pragma unroll
        for (int n = 0; n < 4; ++n)
            #pragma unroll
            for (int j = 0; j < 4; ++j)
                p[m][n][j] = __expf((acc[m][n][j] - 1.0f) * INV_T);

    #pragma unroll
    for (int m = 0; m < 4; ++m)
        #pragma unroll
        for (int j = 0; j < 4; ++j) {
            float rs = p[m][0][j] + p[m][1][j] + p[m][2][j] + p[m][3][j];
            rs += __shfl_xor(rs, 1);
            rs += __shfl_xor(rs, 2);
            rs += __shfl_xor(rs, 4);
            rs += __shfl_xor(rs, 8);
            if ((lane & 15) == 0) {
                const int grow = (int)row0 + wr * 64 + m * 16 + ((lane >> 4) << 2) + j;
                atomicAdd(&rowsum[grow], rs);
            }
        }

    if (r != c) {
        #pragma unroll
        for (int n = 0; n < 4; ++n) {
            float cs = 0.f;
            #pragma unroll
            for (int m = 0; m < 4; ++m)
                #pragma unroll
                for (int j = 0; j < 4; ++j)
                    cs += p[m][n][j];
            cs += __shfl_xor(cs, 16);
            cs += __shfl_xor(cs, 32);
            if (lane < 16) {
                const int gcol = (int)col0 + wc * 64 + n * 16 + lane;
                atomicAdd(&rowsum[gcol], cs);
            }
        }
    }
}

// ---------------------------------------------------------------------------
// Kernel 3: loss = 1/tau + mean(log E_i) - (sum posbuf)/tau/4096
// ---------------------------------------------------------------------------
__global__ __launch_bounds__(1024) void nt_final(const float* __restrict__ rowsum,
                                                 const float* __restrict__ posbuf,
                                                 float* __restrict__ out) {
    __shared__ float redl[1024];
    __shared__ float redp[1024];
    float s = 0.f, ps = 0.f;
    for (int i = threadIdx.x; i < NROW; i += 1024) s += logf(rowsum[i]);
    for (int i = threadIdx.x; i < NBLK_NORM; i += 1024) ps += posbuf[i];
    redl[threadIdx.x] = s;
    redp[threadIdx.x] = ps;
    __syncthreads();
    for (int off = 512; off; off >>= 1) {
        if (threadIdx.x < off) {
            redl[threadIdx.x] += redl[threadIdx.x + off];
            redp[threadIdx.x] += redp[threadIdx.x + off];
        }
        __syncthreads();
    }
    if (threadIdx.x == 0) {
        out[0] = INV_T + redl[0] / (float)NROW - redp[0] * INV_T / (float)BSZ;
    }
}

extern "C" void kernel_launch(void* const* d_in, const int* in_sizes, int n_in,
                              void* d_out, int out_size, void* d_ws, size_t ws_size,
                              hipStream_t stream) {
    const float* z1 = (const float*)d_in[0];
    const float* z2 = (const float*)d_in[1];
    // d_in[2] (labels) unused by the reference computation

    __hip_bfloat16* F = (__hip_bfloat16*)d_ws;
    const size_t FBYTES = (size_t)NROW * DIM * sizeof(__hip_bfloat16);  // 8 MiB
    float* rowsum = (float*)((char*)d_ws + FBYTES);
    float* posbuf = rowsum + NROW;

    nt_norm<<<dim3(NBLK_NORM), dim3(256), 0, stream>>>(z1, z2, F, posbuf, rowsum);
    simexp<<<dim3(2080), dim3(256), 0, stream>>>(F, rowsum);
    nt_final<<<dim3(1), dim3(1024), 0, stream>>>(rowsum, posbuf, (float*)d_out);
}

// Round 5
// 69.090 us; speedup vs baseline: 2.4637x; 1.1940x over previous
//
#include <hip/hip_runtime.h>
#include <hip/hip_bf16.h>

#define BSZ   4096
#define DIM   512
#define NROW  8192
#define NBLK_NORM (BSZ / 4)
#define INV_T 14.285714285714285f

typedef __bf16 bf16x8 __attribute__((ext_vector_type(8)));
typedef float  f32x4  __attribute__((ext_vector_type(4)));

#define GLOAD_LDS16(gp, lp) __builtin_amdgcn_global_load_lds( \
    (const __attribute__((address_space(1))) unsigned int*)(const void*)(gp), \
    (__attribute__((address_space(3))) unsigned int*)(void*)(lp), 16, 0, 0)

// ---------------------------------------------------------------------------
// Kernel 1: row-normalize z1,z2 -> bf16 F[8192][512]; per-block positive-pair
// dot partials -> posbuf[block]; zeroes rowsum (8 entries/block = full 8192).
// ---------------------------------------------------------------------------
__device__ inline void store_bf4(__hip_bfloat16* p, float4 v, float s) {
    union { __hip_bfloat16 h[4]; uint2 u; } t;
    t.h[0] = __float2bfloat16(v.x * s);
    t.h[1] = __float2bfloat16(v.y * s);
    t.h[2] = __float2bfloat16(v.z * s);
    t.h[3] = __float2bfloat16(v.w * s);
    *(uint2*)p = t.u;
}

__global__ __launch_bounds__(256) void nt_norm(const float* __restrict__ z1,
                                               const float* __restrict__ z2,
                                               __hip_bfloat16* __restrict__ F,
                                               float* __restrict__ posbuf,
                                               float* __restrict__ rowsum) {
    __shared__ float pd[4];
    const int wid  = threadIdx.x >> 6;
    const int lane = threadIdx.x & 63;
    const int row  = blockIdx.x * 4 + wid;          // 0..4095

    if (threadIdx.x < 8) rowsum[blockIdx.x * 8 + threadIdx.x] = 0.0f;

    const float4* a4 = (const float4*)(z1 + (size_t)row * DIM);
    const float4* b4 = (const float4*)(z2 + (size_t)row * DIM);
    float4 a0 = a4[lane], a1 = a4[64 + lane];
    float4 b0 = b4[lane], b1 = b4[64 + lane];

    float s1 = a0.x*a0.x + a0.y*a0.y + a0.z*a0.z + a0.w*a0.w
             + a1.x*a1.x + a1.y*a1.y + a1.z*a1.z + a1.w*a1.w;
    float s2 = b0.x*b0.x + b0.y*b0.y + b0.z*b0.z + b0.w*b0.w
             + b1.x*b1.x + b1.y*b1.y + b1.z*b1.z + b1.w*b1.w;
    float d  = a0.x*b0.x + a0.y*b0.y + a0.z*b0.z + a0.w*b0.w
             + a1.x*b1.x + a1.y*b1.y + a1.z*b1.z + a1.w*b1.w;

    #pragma unroll
    for (int off = 32; off; off >>= 1) {
        s1 += __shfl_xor(s1, off);
        s2 += __shfl_xor(s2, off);
        d  += __shfl_xor(d,  off);
    }

    const float inv1 = 1.0f / fmaxf(sqrtf(s1), 1e-12f);
    const float inv2 = 1.0f / fmaxf(sqrtf(s2), 1e-12f);

    __hip_bfloat16* F1 = F + (size_t)row * DIM;
    __hip_bfloat16* F2 = F + (size_t)(BSZ + row) * DIM;
    store_bf4(F1 + lane * 4,       a0, inv1);
    store_bf4(F1 + 256 + lane * 4, a1, inv1);
    store_bf4(F2 + lane * 4,       b0, inv2);
    store_bf4(F2 + 256 + lane * 4, b1, inv2);

    if (lane == 0) pd[wid] = d * inv1 * inv2;
    __syncthreads();
    if (threadIdx.x == 0)
        posbuf[blockIdx.x] = pd[0] + pd[1] + pd[2] + pd[3];
}

// ---------------------------------------------------------------------------
// Kernel 2: upper-tri 128x128 tile pairs of S = F F^T; p = exp((dot-1)/tau);
// row sums (+ col sums for r!=c) -> rowsum[] atomics.
// 4 waves 2x2, mfma 16x16x32 bf16, BK=64.
// SINGLE-buffered m97 2-barrier loop (32 KB LDS -> 5 blocks/CU, 20 waves/CU;
// inter-block overlap hides latency — m114). Keeps:
// (a) XOR-swizzled LDS (byte ^= (row&7)<<4), rule-#21 involution pair;
// (b) super-tile block order + bijective XCD swizzle (L2-resident panels).
// ---------------------------------------------------------------------------
__device__ __forceinline__ void stage_tiles(const __hip_bfloat16* __restrict__ Ag,
                                            const __hip_bfloat16* __restrict__ Bg,
                                            short* Asb, short* Bsb,
                                            int tid, int wid) {
    #pragma unroll
    for (int ch = 0; ch < 4; ++ch) {
        const int i   = ch * 256 + tid;   // 16B chunk id, 0..1023
        const int rr  = i >> 3;           // tile row
        const int cb  = (i & 7) * 16;     // linear byte col within 128B row
        // inverse-swizzle the SOURCE column so linear LDS dest holds swizzled data
        const int ecs = (cb ^ ((rr & 7) << 4)) >> 1;   // source element col
        const int seg = ch * 256 + wid * 64;           // wave-uniform chunk base
        GLOAD_LDS16(Ag + (size_t)rr * DIM + ecs, Asb + seg * 8);
        GLOAD_LDS16(Bg + (size_t)rr * DIM + ecs, Bsb + seg * 8);
    }
}

__global__ __launch_bounds__(256) void simexp(const __hip_bfloat16* __restrict__ F,
                                              float* __restrict__ rowsum) {
    __shared__ __align__(16) short As[128 * 64];   // 16 KB
    __shared__ __align__(16) short Bs[128 * 64];   // 16 KB

    // ---- block id -> (r,c), super-tile order + bijective XCD swizzle ----
    int L = (blockIdx.x & 7) * 260 + (blockIdx.x >> 3);
    int rem = L, s_r = 0;
    for (; s_r < 8; ++s_r) {
        const int rowsz = 36 + 64 * (7 - s_r);
        if (rem < rowsz) break;
        rem -= rowsz;
    }
    int s_c, lr, lc;
    if (rem < 36) {              // diagonal super-tile, triangular 8x8
        s_c = s_r;
        lr = 0;
        while (rem >= 8 - lr) { rem -= 8 - lr; ++lr; }
        lc = lr + rem;
    } else {                     // off-diagonal super-tiles
        rem -= 36;
        s_c = s_r + 1 + (rem >> 6);
        const int j = rem & 63;
        lr = j >> 3; lc = j & 7;
    }
    const int r = s_r * 8 + lr;
    const int c = s_c * 8 + lc;

    const int tid  = threadIdx.x;
    const int wid  = tid >> 6;
    const int lane = tid & 63;
    const int wr   = wid >> 1;            // wave row (0..1) -> 64 rows
    const int wc   = wid & 1;             // wave col (0..1) -> 64 cols
    const size_t row0 = (size_t)r * 128;
    const size_t col0 = (size_t)c * 128;
    const __hip_bfloat16* Abase = F + row0 * DIM;
    const __hip_bfloat16* Bbase = F + col0 * DIM;

    f32x4 acc[4][4] = {};

    for (int kt = 0; kt < 8; ++kt) {
        stage_tiles(Abase + kt * 64, Bbase + kt * 64, As, Bs, tid, wid);
        __syncthreads();

        #pragma unroll
        for (int ks = 0; ks < 2; ++ks) {
            bf16x8 a[4], b[4];
            const int kb = ks * 64 + ((lane >> 4) << 4);
            const int sw = ((lane & 7) << 4);      // (row&7)<<4, row%8 == lane%8
            #pragma unroll
            for (int m = 0; m < 4; ++m) {
                const int rr = wr * 64 + m * 16 + (lane & 15);
                a[m] = *(const bf16x8*)((const char*)As + rr * 128 + (kb ^ sw));
            }
            #pragma unroll
            for (int n = 0; n < 4; ++n) {
                const int rr = wc * 64 + n * 16 + (lane & 15);
                b[n] = *(const bf16x8*)((const char*)Bs + rr * 128 + (kb ^ sw));
            }
            #pragma unroll
            for (int m = 0; m < 4; ++m)
                #pragma unroll
                for (int n = 0; n < 4; ++n)
                    acc[m][n] = __builtin_amdgcn_mfma_f32_16x16x32_bf16(
                        a[m], b[n], acc[m][n], 0, 0, 0);
        }
        __syncthreads();   // protect LDS from next kt's stage
    }

    // epilogue: p = exp((dot-1)/tau); C/D map col=lane&15, row=(lane>>4)*4+j
    float p[4][4][4];
    #pragma unroll
    for (int m = 0; m < 4; ++m)
        #pragma unroll
        for (int n = 0; n < 4; ++n)
            #pragma unroll
            for (int j = 0; j < 4; ++j)
                p[m][n][j] = __expf((acc[m][n][j] - 1.0f) * INV_T);

    #pragma unroll
    for (int m = 0; m < 4; ++m)
        #pragma unroll
        for (int j = 0; j < 4; ++j) {
            float rs = p[m][0][j] + p[m][1][j] + p[m][2][j] + p[m][3][j];
            rs += __shfl_xor(rs, 1);
            rs += __shfl_xor(rs, 2);
            rs += __shfl_xor(rs, 4);
            rs += __shfl_xor(rs, 8);
            if ((lane & 15) == 0) {
                const int grow = (int)row0 + wr * 64 + m * 16 + ((lane >> 4) << 2) + j;
                atomicAdd(&rowsum[grow], rs);
            }
        }

    if (r != c) {
        #pragma unroll
        for (int n = 0; n < 4; ++n) {
            float cs = 0.f;
            #pragma unroll
            for (int m = 0; m < 4; ++m)
                #pragma unroll
                for (int j = 0; j < 4; ++j)
                    cs += p[m][n][j];
            cs += __shfl_xor(cs, 16);
            cs += __shfl_xor(cs, 32);
            if (lane < 16) {
                const int gcol = (int)col0 + wc * 64 + n * 16 + lane;
                atomicAdd(&rowsum[gcol], cs);
            }
        }
    }
}

// ---------------------------------------------------------------------------
// Kernel 3: loss = 1/tau + mean(log E_i) - (sum posbuf)/tau/4096
// ---------------------------------------------------------------------------
__global__ __launch_bounds__(1024) void nt_final(const float* __restrict__ rowsum,
                                                 const float* __restrict__ posbuf,
                                                 float* __restrict__ out) {
    __shared__ float redl[1024];
    __shared__ float redp[1024];
    float s = 0.f, ps = 0.f;
    for (int i = threadIdx.x; i < NROW; i += 1024) s += logf(rowsum[i]);
    for (int i = threadIdx.x; i < NBLK_NORM; i += 1024) ps += posbuf[i];
    redl[threadIdx.x] = s;
    redp[threadIdx.x] = ps;
    __syncthreads();
    for (int off = 512; off; off >>= 1) {
        if (threadIdx.x < off) {
            redl[threadIdx.x] += redl[threadIdx.x + off];
            redp[threadIdx.x] += redp[threadIdx.x + off];
        }
        __syncthreads();
    }
    if (threadIdx.x == 0) {
        out[0] = INV_T + redl[0] / (float)NROW - redp[0] * INV_T / (float)BSZ;
    }
}

extern "C" void kernel_launch(void* const* d_in, const int* in_sizes, int n_in,
                              void* d_out, int out_size, void* d_ws, size_t ws_size,
                              hipStream_t stream) {
    const float* z1 = (const float*)d_in[0];
    const float* z2 = (const float*)d_in[1];
    // d_in[2] (labels) unused by the reference computation

    __hip_bfloat16* F = (__hip_bfloat16*)d_ws;
    const size_t FBYTES = (size_t)NROW * DIM * sizeof(__hip_bfloat16);  // 8 MiB
    float* rowsum = (float*)((char*)d_ws + FBYTES);
    float* posbuf = rowsum + NROW;

    nt_norm<<<dim3(NBLK_NORM), dim3(256), 0, stream>>>(z1, z2, F, posbuf, rowsum);
    simexp<<<dim3(2080), dim3(256), 0, stream>>>(F, rowsum);
    nt_final<<<dim3(1), dim3(1024), 0, stream>>>(rowsum, posbuf, (float*)d_out);
}